// Round 1
// baseline (815.919 us; speedup 1.0000x reference)
//
#include <hip/hip_runtime.h>
#include <math.h>

// DynamicSparseAttention: out = sum_j w_j V_j / sum_j w_j,  w_j = p_j^5 + p_j,
// p = softmax(Q K^T) (unscaled, per reference). Single-pass flash with dual
// accumulators: w_j = e_j^5 + e_j * Z^4 (e_j = exp(s_j - m), Z = sum e_j).

constexpr int Bc = 2, Lc = 2048, Sc = 2048, Hc = 16, Ec = 64, Dc = 64;
constexpr int PAD = 68;  // floats per LDS row: 272 B, 16B-aligned for b128 ops

__device__ __forceinline__ float4 ld4(const float* row, int c4, int sw) {
  return ((const float4*)row)[c4 ^ sw];
}
__device__ __forceinline__ void st4(float* row, int c4, int sw, float4 val) {
  ((float4*)row)[c4 ^ sw] = val;
}

// 64 rows x 64 floats from global (row stride 1024 floats) into swizzled LDS tile
__device__ __forceinline__ void load_tile64(float (*dst)[PAD], const float* gbase, int tid) {
#pragma unroll
  for (int i = 0; i < 4; ++i) {
    int f4i = i * 256 + tid;
    int row = f4i >> 4, c4 = f4i & 15;
    float4 val = *(const float4*)(gbase + (size_t)row * 1024 + c4 * 4);
    st4(dst[row], c4, row >> 4, val);
  }
}

__global__ __launch_bounds__(256, 3) void dsa_fwd(
    const float* __restrict__ Q, const float* __restrict__ K,
    const float* __restrict__ V, float* __restrict__ O) {
  __shared__ float Qs[64][PAD];
  __shared__ float Ks[64][PAD];  // reused as e-tile after scores are consumed
  __shared__ float Vs[64][PAD];

  const int tid = threadIdx.x;
  const int qt = blockIdx.x;  // query tile 0..31
  const int bh = blockIdx.y;  // 0..31
  const int b = bh >> 4, h = bh & 15;

  const float* qbase = Q + ((size_t)((b * Lc + qt * 64) * Hc + h)) * Ec;
  const float* kbase = K + ((size_t)(b * Sc * Hc + h)) * Ec;
  const float* vbase = V + ((size_t)(b * Sc * Hc + h)) * Dc;

  load_tile64(Qs, qbase, tid);

  // thread owns rows r0..r0+3 (queries) x cols c0..c0+3 (keys / output dims)
  const int g = tid >> 4, m = tid & 15;
  const int r0 = g * 4, c0 = m * 4;
  const int wv = tid >> 6;  // == (r0+i)>>4 for all i: this thread's row swizzle

  float O1[4][4] = {}, O5[4][4] = {};
  float mr[4], S1[4] = {}, S5[4] = {};
#pragma unroll
  for (int i = 0; i < 4; ++i) mr[i] = -INFINITY;

  for (int ks = 0; ks < Sc / 64; ++ks) {
    __syncthreads();  // previous iteration done with Ks(e-tile)/Vs
    load_tile64(Ks, kbase + (size_t)ks * 64 * 1024, tid);
    load_tile64(Vs, vbase + (size_t)ks * 64 * 1024, tid);
    __syncthreads();

    // ---- scores: acc[i][j] = Q[r0+i] . K[c0+j] over E=64 ----
    float acc[4][4] = {};
#pragma unroll
    for (int e4 = 0; e4 < 16; ++e4) {
      float4 q4[4], k4[4];
#pragma unroll
      for (int i = 0; i < 4; ++i) q4[i] = ld4(Qs[r0 + i], e4, wv);
#pragma unroll
      for (int j = 0; j < 4; ++j) k4[j] = ld4(Ks[c0 + j], e4, (c0 + j) >> 4);
#pragma unroll
      for (int i = 0; i < 4; ++i)
#pragma unroll
        for (int j = 0; j < 4; ++j) {
          acc[i][j] = fmaf(q4[i].x, k4[j].x, acc[i][j]);
          acc[i][j] = fmaf(q4[i].y, k4[j].y, acc[i][j]);
          acc[i][j] = fmaf(q4[i].z, k4[j].z, acc[i][j]);
          acc[i][j] = fmaf(q4[i].w, k4[j].w, acc[i][j]);
        }
    }
    __syncthreads();  // everyone done reading Ks before e-tile overwrite

    // ---- online softmax bookkeeping; write e-tile into Ks ----
#pragma unroll
    for (int i = 0; i < 4; ++i) {
      float lm = fmaxf(fmaxf(acc[i][0], acc[i][1]), fmaxf(acc[i][2], acc[i][3]));
#pragma unroll
      for (int off = 1; off < 16; off <<= 1) lm = fmaxf(lm, __shfl_xor(lm, off));
      float nm = fmaxf(mr[i], lm);
      float f = __expf(mr[i] - nm);
      float f2 = f * f, f5 = f2 * f2 * f;
      mr[i] = nm;
      float e0 = __expf(acc[i][0] - nm), e1 = __expf(acc[i][1] - nm);
      float e2 = __expf(acc[i][2] - nm), e3 = __expf(acc[i][3] - nm);
      float t1 = e0 + e1 + e2 + e3;
      float p0 = e0 * e0, p1 = e1 * e1, p2 = e2 * e2, p3 = e3 * e3;
      float t5 = p0 * p0 * e0 + p1 * p1 * e1 + p2 * p2 * e2 + p3 * p3 * e3;
#pragma unroll
      for (int off = 1; off < 16; off <<= 1) {
        t1 += __shfl_xor(t1, off);
        t5 += __shfl_xor(t5, off);
      }
      S1[i] = S1[i] * f + t1;
      S5[i] = S5[i] * f5 + t5;
#pragma unroll
      for (int d = 0; d < 4; ++d) { O1[i][d] *= f; O5[i][d] *= f5; }
      st4(Ks[r0 + i], m, wv, make_float4(e0, e1, e2, e3));  // e-tile row r0+i, cols c0..c0+3
    }
    __syncthreads();

    // ---- PV: O1 += e * V, O5 += e^5 * V ----
#pragma unroll 8
    for (int j = 0; j < 64; ++j) {
      float4 vv = ld4(Vs[j], m, j >> 4);
      const int ebase = (((j >> 2) ^ wv) << 2) | (j & 3);  // scalar slot of col j
#pragma unroll
      for (int i = 0; i < 4; ++i) {
        float e = Ks[r0 + i][ebase];
        float e2 = e * e;
        float e5 = e2 * e2 * e;
        O1[i][0] = fmaf(e, vv.x, O1[i][0]);
        O1[i][1] = fmaf(e, vv.y, O1[i][1]);
        O1[i][2] = fmaf(e, vv.z, O1[i][2]);
        O1[i][3] = fmaf(e, vv.w, O1[i][3]);
        O5[i][0] = fmaf(e5, vv.x, O5[i][0]);
        O5[i][1] = fmaf(e5, vv.y, O5[i][1]);
        O5[i][2] = fmaf(e5, vv.z, O5[i][2]);
        O5[i][3] = fmaf(e5, vv.w, O5[i][3]);
      }
    }
  }

  // ---- epilogue: out = (O5 + Z^4 O1) / (S5 + Z^4 S1), Z = S1 ----
  float* obase = O + ((size_t)((b * Lc + qt * 64) * Hc + h)) * Dc;
#pragma unroll
  for (int i = 0; i < 4; ++i) {
    float z = S1[i], z2 = z * z, z4 = z2 * z2;
    float inv = 1.0f / (S5[i] + z4 * S1[i]);
    float4 o;
    o.x = (O5[i][0] + z4 * O1[i][0]) * inv;
    o.y = (O5[i][1] + z4 * O1[i][1]) * inv;
    o.z = (O5[i][2] + z4 * O1[i][2]) * inv;
    o.w = (O5[i][3] + z4 * O1[i][3]) * inv;
    *(float4*)(obase + (size_t)(r0 + i) * 1024 + c0) = o;
  }
}

extern "C" void kernel_launch(void* const* d_in, const int* in_sizes, int n_in,
                              void* d_out, int out_size, void* d_ws, size_t ws_size,
                              hipStream_t stream) {
  const float* q = (const float*)d_in[0];
  const float* k = (const float*)d_in[1];
  const float* v = (const float*)d_in[2];
  float* o = (float*)d_out;
  dim3 grid(Lc / 64, Bc * Hc);
  dsa_fwd<<<grid, dim3(256), 0, stream>>>(q, k, v, o);
}

// Round 2
// 95.905 us; speedup vs baseline: 8.5076x; 8.5076x over previous
//
#include <hip/hip_runtime.h>
#include <math.h>

// DynamicSparseAttention via MFMA flash:
// out = (O5 + Z^4 O1) / (S5 + Z^4 S1), e = 2^(s*log2e - m'), Z = S1.
// Swapped QK^T (mfma(K,Q)) so each lane owns one query's score row.

typedef _Float16 h8 __attribute__((ext_vector_type(8)));
typedef _Float16 h4 __attribute__((ext_vector_type(4)));
typedef _Float16 h2 __attribute__((ext_vector_type(2)));
typedef float f4 __attribute__((ext_vector_type(4)));

constexpr int Bc = 2, Lc = 2048, Sc = 2048, Hc = 16, Ec = 64, Dc = 64;
constexpr int QB = 128, KB = 64, NT = Sc / KB;
constexpr float LOG2E = 1.4426950408889634f;

__device__ __forceinline__ f4 mm(h8 a, h8 b, f4 c) {
  return __builtin_amdgcn_mfma_f32_16x16x32_f16(a, b, c, 0, 0, 0);
}

__global__ __launch_bounds__(256, 2) void dsa_mfma(
    const float* __restrict__ Q, const float* __restrict__ K,
    const float* __restrict__ V, float* __restrict__ O) {
  __shared__ __align__(16) _Float16 Ks[64 * 64];        // K tile [k][e], swizzled
  __shared__ __align__(16) _Float16 Vts[64 * 64];       // V^T tile [d][k], swizzled
  __shared__ __align__(16) _Float16 Ps[4][2][32 * 64];  // per-wave P (e, e5) [q][k]

  const int tid = threadIdx.x;
  const int w = tid >> 6, lane = tid & 63, lq = lane & 15, lg = lane >> 4;
  const int kxor = (lq & 7) << 3;

  // XCD-bijective swizzle: 512 blocks = 8 XCD x 64; each XCD owns 4 heads.
  const int blk = blockIdx.x;
  const int ww = (blk & 7) * 64 + (blk >> 3);
  const int qtb = ww & 15, bh = ww >> 4;
  const int b = bh >> 4, h = bh & 15;

  const size_t qbase = (size_t)b * Lc * Hc * Ec + (size_t)h * Ec;
  const size_t kbase = (size_t)b * Sc * Hc * Ec + (size_t)h * Ec;
  const size_t vbase = (size_t)b * Sc * Hc * Dc + (size_t)h * Dc;
  const int q0 = qtb * QB + w * 32;

  // ---- Q fragments to registers, scaled by log2e ----
  h8 qf[2][2];  // [qt][kstep]
#pragma unroll
  for (int qt = 0; qt < 2; ++qt)
#pragma unroll
    for (int ks = 0; ks < 2; ++ks) {
      const float* p = Q + qbase + (size_t)(q0 + qt * 16 + lq) * 1024 + ks * 32 + lg * 8;
      f4 a = *(const f4*)p, c = *(const f4*)(p + 4);
#pragma unroll
      for (int i = 0; i < 4; ++i) {
        qf[qt][ks][i] = (_Float16)(a[i] * LOG2E);
        qf[qt][ks][4 + i] = (_Float16)(c[i] * LOG2E);
      }
    }

  f4 O1[4][2] = {}, O5[4][2] = {};  // [dtile][qt]
  float mr[2] = {-INFINITY, -INFINITY}, S1[2] = {0.f, 0.f}, S5[2] = {0.f, 0.f};

  f4 kf[4], va[2], vb[2];  // staging registers

  auto LOADK = [&](int k0) {
#pragma unroll
    for (int i = 0; i < 4; ++i) {
      int idx = i * 256 + tid;
      int krow = idx >> 4, kc4 = idx & 15;
      kf[i] = *(const f4*)(K + kbase + (size_t)(k0 + krow) * 1024 + kc4 * 4);
    }
  };
  auto LOADV = [&](int k0) {
#pragma unroll
    for (int i = 0; i < 2; ++i) {
      int idx = i * 256 + tid;
      int dq = idx & 15, kp = idx >> 4;
      const float* p = V + vbase + (size_t)(k0 + 2 * kp) * 1024 + dq * 4;
      va[i] = *(const f4*)p;
      vb[i] = *(const f4*)(p + 1024);
    }
  };
  auto STORE = [&]() {
#pragma unroll
    for (int i = 0; i < 4; ++i) {
      int idx = i * 256 + tid;
      int krow = idx >> 4, kc4 = idx & 15;
      int col = (kc4 * 4) ^ ((krow & 7) << 3);
      h4 hh;
#pragma unroll
      for (int j = 0; j < 4; ++j) hh[j] = (_Float16)kf[i][j];
      *(h4*)&Ks[krow * 64 + col] = hh;
    }
#pragma unroll
    for (int i = 0; i < 2; ++i) {
      int idx = i * 256 + tid;
      int dq = idx & 15, kp = idx >> 4;
#pragma unroll
      for (int j = 0; j < 4; ++j) {
        int d = dq * 4 + j;
        int col = (2 * kp) ^ ((d & 7) << 3);
        h2 hh = {(_Float16)va[i][j], (_Float16)vb[i][j]};
        *(h2*)&Vts[d * 64 + col] = hh;
      }
    }
  };

  LOADK(0);
  LOADV(0);

#pragma unroll 1
  for (int ks = 0; ks < NT; ++ks) {
    __syncthreads();  // prior tile's consumers done with Ks/Vts
    STORE();
    if (ks + 1 < NT) {  // prefetch next tile; latency hides under compute
      LOADK((ks + 1) * KB);
      LOADV((ks + 1) * KB);
    }
    __syncthreads();  // staged tile visible

    // ---- QK^T (swapped): sc[qt][mt] = D[k][q] ----
    f4 sc[2][4] = {};
#pragma unroll
    for (int kk = 0; kk < 2; ++kk)
#pragma unroll
      for (int mt = 0; mt < 4; ++mt) {
        h8 kf8 = *(const h8*)&Ks[(mt * 16 + lq) * 64 + ((kk * 32 + lg * 8) ^ kxor)];
        sc[0][mt] = mm(kf8, qf[0][kk], sc[0][mt]);
        sc[1][mt] = mm(kf8, qf[1][kk], sc[1][mt]);
      }

    // ---- online softmax (log2 domain), write P tiles ----
#pragma unroll
    for (int qt = 0; qt < 2; ++qt) {
      float tm = -INFINITY;
#pragma unroll
      for (int mt = 0; mt < 4; ++mt)
#pragma unroll
        for (int r = 0; r < 4; ++r) tm = fmaxf(tm, sc[qt][mt][r]);
      tm = fmaxf(tm, __shfl_xor(tm, 16));
      tm = fmaxf(tm, __shfl_xor(tm, 32));
      if (__any(tm > mr[qt])) {  // rescale only on a new running max
        float nm = fmaxf(mr[qt], tm);
        float f = __builtin_amdgcn_exp2f(mr[qt] - nm);
        float f2 = f * f, f5 = f2 * f2 * f;
        mr[qt] = nm;
        S1[qt] *= f;
        S5[qt] *= f5;
#pragma unroll
        for (int dt = 0; dt < 4; ++dt) {
          O1[dt][qt] *= f;
          O5[dt][qt] *= f5;
        }
      }
      float t1 = 0.f, t5 = 0.f;
#pragma unroll
      for (int mt = 0; mt < 4; ++mt) {
        h4 pe, p5;
#pragma unroll
        for (int r = 0; r < 4; ++r) {
          float e = __builtin_amdgcn_exp2f(sc[qt][mt][r] - mr[qt]);
          float e2 = e * e, e5v = e2 * e2 * e;
          t1 += e;
          t5 += e5v;
          pe[r] = (_Float16)e;
          p5[r] = (_Float16)e5v;
        }
        int pcol = (mt * 16 + lg * 4) ^ kxor;
        *(h4*)&Ps[w][0][(qt * 16 + lq) * 64 + pcol] = pe;
        *(h4*)&Ps[w][1][(qt * 16 + lq) * 64 + pcol] = p5;
      }
      t1 += __shfl_xor(t1, 16);
      t1 += __shfl_xor(t1, 32);
      t5 += __shfl_xor(t5, 16);
      t5 += __shfl_xor(t5, 32);
      S1[qt] += t1;
      S5[qt] += t5;
    }

    // ---- PV (dual): O^T[d][q] += V^T P ----
#pragma unroll
    for (int k2 = 0; k2 < 2; ++k2) {
      h8 vf[4];
#pragma unroll
      for (int dt = 0; dt < 4; ++dt)
        vf[dt] = *(const h8*)&Vts[(dt * 16 + lq) * 64 + ((k2 * 32 + lg * 8) ^ kxor)];
#pragma unroll
      for (int qt = 0; qt < 2; ++qt) {
        h8 be = *(const h8*)&Ps[w][0][(qt * 16 + lq) * 64 + ((k2 * 32 + lg * 8) ^ kxor)];
        h8 b5 = *(const h8*)&Ps[w][1][(qt * 16 + lq) * 64 + ((k2 * 32 + lg * 8) ^ kxor)];
#pragma unroll
        for (int dt = 0; dt < 4; ++dt) {
          O1[dt][qt] = mm(vf[dt], be, O1[dt][qt]);
          O5[dt][qt] = mm(vf[dt], b5, O5[dt][qt]);
        }
      }
    }
  }

  // ---- epilogue: combine and normalize ----
  const size_t obase = (size_t)b * Lc * Hc * Dc + (size_t)h * Dc;
#pragma unroll
  for (int qt = 0; qt < 2; ++qt) {
    float z = S1[qt], z2 = z * z, z4 = z2 * z2;
    float inv = 1.0f / (S5[qt] + z4 * S1[qt]);
#pragma unroll
    for (int dt = 0; dt < 4; ++dt) {
      f4 o = (O5[dt][qt] + z4 * O1[dt][qt]) * inv;
      *(f4*)(O + obase + (size_t)(q0 + qt * 16 + lq) * 1024 + dt * 16 + lg * 4) = o;
    }
  }
}

extern "C" void kernel_launch(void* const* d_in, const int* in_sizes, int n_in,
                              void* d_out, int out_size, void* d_ws, size_t ws_size,
                              hipStream_t stream) {
  const float* q = (const float*)d_in[0];
  const float* k = (const float*)d_in[1];
  const float* v = (const float*)d_in[2];
  float* o = (float*)d_out;
  dsa_mfma<<<dim3(512), dim3(256), 0, stream>>>(q, k, v, o);
}